// Round 1
// baseline (210.588 us; speedup 1.0000x reference)
//
#include <hip/hip_runtime.h>
#include <math.h>

#define BB 4
#define NN 2048
#define CIN 64
#define HID 128
#define HEADS 4
#define DD 32
#define NQ 16
#define NEG_SLOPE 0.2f

#define TI 8          // i-rows per attention block
#define JT 256        // j-tile
#define WSTR 260      // padded LDS row stride (260*4 bytes, 16B aligned)
#define KTOT (NN*HID) // 262144
#define CCH 256       // k_proj blocks

// ---------------- Kernel A: h = x@W_in + b, alpha_src/dst ----------------
__global__ __launch_bounds__(256) void k_hidden(
    const float* __restrict__ x, const float* __restrict__ W_in,
    const float* __restrict__ b_in, const float* __restrict__ att_src,
    const float* __restrict__ att_dst, float* __restrict__ hT,
    float* __restrict__ srcA, float* __restrict__ dstA)
{
    __shared__ float Wl[CIN * HID];   // 32 KB
    __shared__ float xl[2][CIN];
    const int t = threadIdx.x;

    for (int idx = t; idx < CIN * HID; idx += 256) Wl[idx] = W_in[idx];

    const int jj0 = blockIdx.x * 2;
    if (t < 2 * CIN) {
        int r = t / CIN, k = t % CIN;
        xl[r][k] = x[(size_t)(jj0 + r) * CIN + k];
    }
    __syncthreads();

    const int c = t & 127;
    const int r = t >> 7;
    const int jj = jj0 + r;
    const int b = jj >> 11;
    const int j = jj & (NN - 1);

    float acc = b_in[c];
#pragma unroll 8
    for (int k = 0; k < CIN; ++k)
        acc = fmaf(xl[r][k], Wl[k * HID + c], acc);

    hT[((size_t)(b * HID + c)) * NN + j] = acc;

    const int h = c >> 5, d = c & 31;
    float vs = acc * att_src[h * DD + d];
    float vd = acc * att_dst[h * DD + d];
#pragma unroll
    for (int m = 16; m >= 1; m >>= 1) {
        vs += __shfl_xor(vs, m, 64);
        vd += __shfl_xor(vd, m, 64);
    }
    if ((t & 31) == 0) {
        srcA[(size_t)(b * HEADS + h) * NN + j] = vs;
        dstA[(size_t)(b * HEADS + h) * NN + j] = vd;
    }
}

// ---------------- Kernel B: masked softmax attention + aggregation ----------------
__global__ __launch_bounds__(256) void k_attn(
    const int* __restrict__ adj, const float* __restrict__ hT,
    const float* __restrict__ srcA, const float* __restrict__ dstA,
    float* __restrict__ attO)
{
    __shared__ float w_lds[32 * WSTR];   // 33.3 KB
    __shared__ float wred[4][32];
    __shared__ float wsum_f[32];

    const int t = threadIdx.x;
    const int bx = blockIdx.x;
    const int b = bx >> 8;               // N/TI = 256 groups
    const int ig = bx & 255;
    const int i0 = ig * TI;

    // phase-1 role
    const int ih = t & 31;               // = ii*4 + hh
    const int ii = ih >> 2;
    const int hh = ih & 3;
    const int sub = t >> 5;              // 8 j-subsets
    const int i_glob = i0 + ii;
    const float srci = srcA[(size_t)(b * HEADS + hh) * NN + i_glob];
    const int* adjrow = adj + (size_t)i_glob * NN;
    const float* dstrow = dstA + (size_t)(b * HEADS + hh) * NN;

    // phase-2 role
    const int c = t & 127;               // = h2*32 + d2
    const int h2 = c >> 5;
    const int cp = t >> 7;               // 2 j-half copies
    const float* hrow = hT + (size_t)(b * HID + c) * NN;

    float acc[TI];
#pragma unroll
    for (int i = 0; i < TI; ++i) acc[i] = 0.f;
    float pw = 0.f;

    for (int tile = 0; tile < NN / JT; ++tile) {
        const int jt = tile * JT;
        // ---- phase 1: compute w into LDS ----
        const int jbase = jt + sub * 32;
#pragma unroll
        for (int jj4 = 0; jj4 < 32; jj4 += 4) {
            const int jg = jbase + jj4;
            const int4 a4 = *(const int4*)(adjrow + jg);
            const float4 d4 = *(const float4*)(dstrow + jg);
            float4 wv;
            float s;
            s = srci + d4.x; s = (s >= 0.f) ? s : NEG_SLOPE * s; wv.x = a4.x ? __expf(s) : 0.f;
            s = srci + d4.y; s = (s >= 0.f) ? s : NEG_SLOPE * s; wv.y = a4.y ? __expf(s) : 0.f;
            s = srci + d4.z; s = (s >= 0.f) ? s : NEG_SLOPE * s; wv.z = a4.z ? __expf(s) : 0.f;
            s = srci + d4.w; s = (s >= 0.f) ? s : NEG_SLOPE * s; wv.w = a4.w ? __expf(s) : 0.f;
            *(float4*)(&w_lds[ih * WSTR + (sub * 32 + jj4)]) = wv;
            pw += wv.x + wv.y + wv.z + wv.w;
        }
        __syncthreads();
        // ---- phase 2: acc[i] += w[i][h2][j] * hT[c][j] ----
        const float* hrow_t = hrow + jt + cp * 128;
        const int wcol = cp * 128;
#pragma unroll 4
        for (int js = 0; js < 128; js += 4) {
            const float4 hv = *(const float4*)(hrow_t + js);
#pragma unroll
            for (int i = 0; i < TI; ++i) {
                const float4 wv = *(const float4*)(&w_lds[(i * 4 + h2) * WSTR + wcol + js]);
                acc[i] = fmaf(wv.x, hv.x, acc[i]);
                acc[i] = fmaf(wv.y, hv.y, acc[i]);
                acc[i] = fmaf(wv.z, hv.z, acc[i]);
                acc[i] = fmaf(wv.w, hv.w, acc[i]);
            }
        }
        __syncthreads();
    }

    // ---- reduce wsum over 8 subs ----
    float pw2 = pw + __shfl_xor(pw, 32, 64);
    const int lane = t & 63, wave = t >> 6;
    if (lane < 32) wred[wave][lane] = pw2;
    // ---- combine the two j-half copies via LDS (reuse w_lds) ----
    if (cp) {
#pragma unroll
        for (int i = 0; i < TI; ++i) w_lds[i * 128 + c] = acc[i];
    }
    __syncthreads();
    if (t < 32) wsum_f[t] = wred[0][t] + wred[1][t] + wred[2][t] + wred[3][t];
    __syncthreads();
    if (!cp) {
#pragma unroll
        for (int i = 0; i < TI; ++i) {
            const float v = acc[i] + w_lds[i * 128 + c];
            attO[(size_t)(b * NN + i0 + i) * HID + c] = v / wsum_f[i * 4 + h2];
        }
    }
}

// ---------------- init d_out with bias ----------------
__global__ void k_init(const float* __restrict__ b_out, float* __restrict__ dout)
{
    const int t = threadIdx.x; // 64 threads
    dout[t] = b_out[t & 15];
}

// ---------------- Kernel C: final projection ----------------
__global__ __launch_bounds__(256) void k_proj(
    const float* __restrict__ attO, const float* __restrict__ W_out,
    float* __restrict__ dout)
{
    const int t = threadIdx.x;
    const int k0 = blockIdx.x * (KTOT / CCH);   // 1024 k per block

    float acc[64];
#pragma unroll
    for (int r = 0; r < 64; ++r) acc[r] = 0.f;

    for (int s = 0; s < (KTOT / CCH) / 256; ++s) {
        const int k = k0 + s * 256 + t;
        float a[4];
#pragma unroll
        for (int b = 0; b < 4; ++b) a[b] = attO[(size_t)b * KTOT + k];
        const float4* wr = (const float4*)(W_out + (size_t)k * NQ);
        float wf[16];
#pragma unroll
        for (int q4 = 0; q4 < 4; ++q4) {
            const float4 w4 = wr[q4];
            wf[q4 * 4 + 0] = w4.x; wf[q4 * 4 + 1] = w4.y;
            wf[q4 * 4 + 2] = w4.z; wf[q4 * 4 + 3] = w4.w;
        }
#pragma unroll
        for (int b = 0; b < 4; ++b)
#pragma unroll
            for (int q = 0; q < 16; ++q)
                acc[b * 16 + q] = fmaf(a[b], wf[q], acc[b * 16 + q]);
    }

    const int lane = t & 63, wave = t >> 6;
    __shared__ float red[4][64];
#pragma unroll
    for (int r = 0; r < 64; ++r) {
        float v = acc[r];
        v += __shfl_down(v, 32, 64);
        v += __shfl_down(v, 16, 64);
        v += __shfl_down(v, 8, 64);
        v += __shfl_down(v, 4, 64);
        v += __shfl_down(v, 2, 64);
        v += __shfl_down(v, 1, 64);
        if (lane == 0) red[wave][r] = v;
    }
    __syncthreads();
    if (t < 64) {
        const float v = red[0][t] + red[1][t] + red[2][t] + red[3][t];
        atomicAdd(&dout[t], v);
    }
}

extern "C" void kernel_launch(void* const* d_in, const int* in_sizes, int n_in,
                              void* d_out, int out_size, void* d_ws, size_t ws_size,
                              hipStream_t stream)
{
    const float* x       = (const float*)d_in[0];
    const int*   adj     = (const int*)d_in[1];
    const float* W_in    = (const float*)d_in[2];
    const float* b_in    = (const float*)d_in[3];
    const float* att_src = (const float*)d_in[4];
    const float* att_dst = (const float*)d_in[5];
    const float* W_out   = (const float*)d_in[6];
    const float* b_out   = (const float*)d_in[7];
    float* out = (float*)d_out;

    float* ws   = (float*)d_ws;
    float* hT   = ws;                                   // B*HID*N
    float* srcA = hT + (size_t)BB * HID * NN;           // B*HEADS*N
    float* dstA = srcA + (size_t)BB * HEADS * NN;       // B*HEADS*N
    float* attO = dstA + (size_t)BB * HEADS * NN;       // B*N*HID

    k_hidden<<<BB * NN / 2, 256, 0, stream>>>(x, W_in, b_in, att_src, att_dst, hT, srcA, dstA);
    k_attn<<<BB * (NN / TI), 256, 0, stream>>>(adj, hT, srcA, dstA, attO);
    k_init<<<1, 64, 0, stream>>>(b_out, out);
    k_proj<<<CCH, 256, 0, stream>>>(attO, W_out, out);
}

// Round 2
// 109.099 us; speedup vs baseline: 1.9303x; 1.9303x over previous
//
#include <hip/hip_runtime.h>
#include <math.h>

#define BB 4
#define NN 2048
#define CIN 64
#define HID 128
#define HEADS 4
#define DD 32
#define NQ 16
#define NEG_SLOPE 0.2f
#define KTOT (NN*HID) // 262144
#define CCH 256       // k_proj blocks
#define LOG2E 1.44269504088896340736f

typedef __attribute__((ext_vector_type(8))) _Float16 half8;
typedef __attribute__((ext_vector_type(4))) float f32x4;

// ---------------- Kernel A: h = x@W_in + b, alpha_src/dst ----------------
__global__ __launch_bounds__(256) void k_hidden(
    const float* __restrict__ x, const float* __restrict__ W_in,
    const float* __restrict__ b_in, const float* __restrict__ att_src,
    const float* __restrict__ att_dst, float* __restrict__ hT,
    float* __restrict__ srcA, float* __restrict__ dstA)
{
    __shared__ float Wl[CIN * HID];   // 32 KB
    __shared__ float xl[2][CIN];
    const int t = threadIdx.x;

    for (int idx = t; idx < CIN * HID; idx += 256) Wl[idx] = W_in[idx];

    const int jj0 = blockIdx.x * 2;
    if (t < 2 * CIN) {
        int r = t / CIN, k = t % CIN;
        xl[r][k] = x[(size_t)(jj0 + r) * CIN + k];
    }
    __syncthreads();

    const int c = t & 127;
    const int r = t >> 7;
    const int jj = jj0 + r;
    const int b = jj >> 11;
    const int j = jj & (NN - 1);

    float acc = b_in[c];
#pragma unroll 8
    for (int k = 0; k < CIN; ++k)
        acc = fmaf(xl[r][k], Wl[k * HID + c], acc);

    hT[((size_t)(b * HID + c)) * NN + j] = acc;

    const int h = c >> 5, d = c & 31;
    float vs = acc * att_src[h * DD + d];
    float vd = acc * att_dst[h * DD + d];
#pragma unroll
    for (int m = 16; m >= 1; m >>= 1) {
        vs += __shfl_xor(vs, m, 64);
        vd += __shfl_xor(vd, m, 64);
    }
    if ((t & 31) == 0) {
        srcA[(size_t)(b * HEADS + h) * NN + j] = vs;
        dstA[(size_t)(b * HEADS + h) * NN + j] = vd;
    }
}

// ---------------- k_cvt: hT f32 -> hH f16 (same layout) ----------------
__global__ __launch_bounds__(256) void k_cvt(const float* __restrict__ hT,
                                             _Float16* __restrict__ hH)
{
    const int idx = (blockIdx.x * 256 + threadIdx.x) * 8;
    const float4 a = *(const float4*)(hT + idx);
    const float4 b = *(const float4*)(hT + idx + 4);
    half8 v;
    v[0] = (_Float16)a.x; v[1] = (_Float16)a.y;
    v[2] = (_Float16)a.z; v[3] = (_Float16)a.w;
    v[4] = (_Float16)b.x; v[5] = (_Float16)b.y;
    v[6] = (_Float16)b.z; v[7] = (_Float16)b.w;
    *(half8*)(hH + idx) = v;
}

// ---------------- k_adjb: adj int32 -> bitmask (bit j of word j/32) ----------------
__global__ __launch_bounds__(256) void k_adjb(const int* __restrict__ adj,
                                              unsigned* __restrict__ adjb)
{
    const int wid = blockIdx.x * 4 + (threadIdx.x >> 6);
    const int lane = threadIdx.x & 63;
    const int i = wid >> 5;            // row
    const int jc = wid & 31;           // 64-col chunk
    const int a = adj[(size_t)i * NN + jc * 64 + lane];
    const unsigned long long m = __ballot(a != 0);
    if (lane == 0) {
        *(uint2*)(adjb + (size_t)i * (NN / 32) + jc * 2) =
            make_uint2((unsigned)m, (unsigned)(m >> 32));
    }
}

// ---------------- Kernel B: MFMA flash-GAT ----------------
// block = 256 thr = 4 waves (one per head); block handles (b, 16-row i-tile)
__global__ __launch_bounds__(256) void k_attn(
    const unsigned* __restrict__ adjb, const _Float16* __restrict__ hH,
    const float* __restrict__ srcA, const float* __restrict__ dstA,
    float* __restrict__ attO)
{
    __shared__ float ldst[HEADS][NN];   // 32 KB, dst*log2e per head
    const int t = threadIdx.x;
    const int lane = t & 63;
    const int h = t >> 6;
    const int b = blockIdx.x >> 7;
    const int i0 = (blockIdx.x & 127) * 16;

    {   // stage this head's dst row, pre-scaled by log2(e)
        const float4* s4 = (const float4*)(dstA + (size_t)(b * HEADS + h) * NN);
        float4* d4 = (float4*)&ldst[h][0];
        for (int k = lane; k < NN / 4; k += 64) {
            float4 v = s4[k];
            v.x *= LOG2E; v.y *= LOG2E; v.z *= LOG2E; v.w *= LOG2E;
            d4[k] = v;
        }
    }
    __syncthreads();

    const int r16 = lane & 15;
    const int g = lane >> 4;
    const float srci = srcA[(size_t)(b * HEADS + h) * NN + i0 + r16] * LOG2E;
    const unsigned* adjrow = adjb + (size_t)(i0 + r16) * (NN / 32);
    const _Float16* bbase = hH + ((size_t)(b * HID) + h * DD + r16) * NN + 8 * g;

    f32x4 acc0 = {0.f, 0.f, 0.f, 0.f};
    f32x4 acc1 = {0.f, 0.f, 0.f, 0.f};
    float rs = 0.f;

#pragma unroll 2
    for (int jt = 0; jt < NN; jt += 32) {
        const unsigned aw = adjrow[jt >> 5];
        const float4 dl0 = *(const float4*)&ldst[h][jt + 8 * g];
        const float4 dl1 = *(const float4*)&ldst[h][jt + 8 * g + 4];
        const half8 b0 = *(const half8*)(bbase + jt);
        const half8 b1 = *(const half8*)(bbase + 16 * NN + jt);
        const unsigned bits = aw >> (8 * g);
        const float dv[8] = {dl0.x, dl0.y, dl0.z, dl0.w, dl1.x, dl1.y, dl1.z, dl1.w};
        half8 af;
#pragma unroll
        for (int e = 0; e < 8; ++e) {
            float s = srci + dv[e];               // score * log2e
            s = (s >= 0.f) ? s : NEG_SLOPE * s;   // lrelu commutes with +scale
            const float w = (bits & (1u << e)) ? exp2f(s) : 0.f;
            rs += w;
            af[e] = (_Float16)w;
        }
        acc0 = __builtin_amdgcn_mfma_f32_16x16x32_f16(af, b0, acc0, 0, 0, 0);
        acc1 = __builtin_amdgcn_mfma_f32_16x16x32_f16(af, b1, acc1, 0, 0, 0);
    }

    // rowsum: reduce across the 4 k-groups (same r16) -> all lanes hold row r16's sum
    rs += __shfl_xor(rs, 16, 64);
    rs += __shfl_xor(rs, 32, 64);

#pragma unroll
    for (int r = 0; r < 4; ++r) {
        const float inv = 1.f / __shfl(rs, 4 * g + r, 64);
        const size_t row = (size_t)(b * NN + i0 + 4 * g + r) * HID + h * DD + r16;
        attO[row]      = acc0[r] * inv;
        attO[row + 16] = acc1[r] * inv;
    }
}

// ---------------- init d_out with bias ----------------
__global__ void k_init(const float* __restrict__ b_out, float* __restrict__ dout)
{
    const int t = threadIdx.x; // 64 threads
    dout[t] = b_out[t & 15];
}

// ---------------- Kernel C: final projection ----------------
__global__ __launch_bounds__(256) void k_proj(
    const float* __restrict__ attO, const float* __restrict__ W_out,
    float* __restrict__ dout)
{
    const int t = threadIdx.x;
    const int k0 = blockIdx.x * (KTOT / CCH);   // 1024 k per block

    float acc[64];
#pragma unroll
    for (int r = 0; r < 64; ++r) acc[r] = 0.f;

    for (int s = 0; s < (KTOT / CCH) / 256; ++s) {
        const int k = k0 + s * 256 + t;
        float a[4];
#pragma unroll
        for (int b = 0; b < 4; ++b) a[b] = attO[(size_t)b * KTOT + k];
        const float4* wr = (const float4*)(W_out + (size_t)k * NQ);
        float wf[16];
#pragma unroll
        for (int q4 = 0; q4 < 4; ++q4) {
            const float4 w4 = wr[q4];
            wf[q4 * 4 + 0] = w4.x; wf[q4 * 4 + 1] = w4.y;
            wf[q4 * 4 + 2] = w4.z; wf[q4 * 4 + 3] = w4.w;
        }
#pragma unroll
        for (int b = 0; b < 4; ++b)
#pragma unroll
            for (int q = 0; q < 16; ++q)
                acc[b * 16 + q] = fmaf(a[b], wf[q], acc[b * 16 + q]);
    }

    const int lane = t & 63, wave = t >> 6;
    __shared__ float red[4][64];
#pragma unroll
    for (int r = 0; r < 64; ++r) {
        float v = acc[r];
        v += __shfl_down(v, 32, 64);
        v += __shfl_down(v, 16, 64);
        v += __shfl_down(v, 8, 64);
        v += __shfl_down(v, 4, 64);
        v += __shfl_down(v, 2, 64);
        v += __shfl_down(v, 1, 64);
        if (lane == 0) red[wave][r] = v;
    }
    __syncthreads();
    if (t < 64) {
        const float v = red[0][t] + red[1][t] + red[2][t] + red[3][t];
        atomicAdd(&dout[t], v);
    }
}

extern "C" void kernel_launch(void* const* d_in, const int* in_sizes, int n_in,
                              void* d_out, int out_size, void* d_ws, size_t ws_size,
                              hipStream_t stream)
{
    const float* x       = (const float*)d_in[0];
    const int*   adj     = (const int*)d_in[1];
    const float* W_in    = (const float*)d_in[2];
    const float* b_in    = (const float*)d_in[3];
    const float* att_src = (const float*)d_in[4];
    const float* att_dst = (const float*)d_in[5];
    const float* W_out   = (const float*)d_in[6];
    const float* b_out   = (const float*)d_in[7];
    float* out = (float*)d_out;

    float* ws = (float*)d_ws;
    float* hT   = ws;                                  // 1,048,576 f32 (4 MB)
    float* attO = ws;                                  // alias: hT dead after k_cvt
    float* srcA = ws + (size_t)BB * HID * NN;          // 32768 f32
    float* dstA = srcA + (size_t)BB * HEADS * NN;      // 32768 f32
    _Float16* hH = (_Float16*)(dstA + (size_t)BB * HEADS * NN);   // 1,048,576 f16 (2 MB)
    unsigned* adjbw = (unsigned*)((char*)hH + sizeof(_Float16) * (size_t)BB * HID * NN); // 512 KB

    k_hidden<<<BB * NN / 2, 256, 0, stream>>>(x, W_in, b_in, att_src, att_dst, hT, srcA, dstA);
    k_adjb<<<NN * (NN / 64) / 4, 256, 0, stream>>>(adj, adjbw);
    k_cvt<<<(BB * HID * NN) / (256 * 8), 256, 0, stream>>>(hT, hH);
    k_attn<<<BB * (NN / 16), 256, 0, stream>>>(adjbw, hH, srcA, dstA, attO);
    k_init<<<1, 64, 0, stream>>>(b_out, out);
    k_proj<<<CCH, 256, 0, stream>>>(attO, W_out, out);
}

// Round 4
// 88.102 us; speedup vs baseline: 2.3903x; 1.2383x over previous
//
#include <hip/hip_runtime.h>
#include <math.h>

#define BB 4
#define NN 2048
#define CIN 64
#define HID 128
#define HEADS 4
#define DD 32
#define NQ 16
#define KTOT (NN*HID) // 262144
#define CCH 256       // k_proj blocks
#define LOG2E 1.44269504088896340736f
#define NEGBIG -100.0f

typedef __attribute__((ext_vector_type(8))) _Float16 half8;
typedef __attribute__((ext_vector_type(2))) _Float16 half2;
typedef __attribute__((ext_vector_type(4))) float f32x4;

// ---------------- Kernel A: h = x@W_in + b (f16 out), alpha_src/dst ----------------
// block = 256 thr handles 16 consecutive jj rows; each thread: one c, 8 consecutive rows.
__global__ __launch_bounds__(256) void k_hidden(
    const float* __restrict__ x, const float* __restrict__ W_in,
    const float* __restrict__ b_in, const float* __restrict__ att_src,
    const float* __restrict__ att_dst, _Float16* __restrict__ hH,
    float* __restrict__ srcA, float* __restrict__ dstA)
{
    __shared__ float Wl[CIN * HID];   // 32 KB
    __shared__ float xl[16][CIN];     // 4 KB
    const int t = threadIdx.x;
    const int jj0 = blockIdx.x * 16;

    {
        const float4* Ws = (const float4*)W_in;
        float4* Wd = (float4*)Wl;
#pragma unroll
        for (int u = 0; u < 8; ++u) Wd[t + 256 * u] = Ws[t + 256 * u];
        ((float4*)&xl[0][0])[t] = ((const float4*)(x + (size_t)jj0 * CIN))[t];
    }
    __syncthreads();

    const int c = t & 127, rg = t >> 7;
    const int b = jj0 >> 11, j0 = jj0 & (NN - 1);
    const int h = c >> 5;

    float acc[8];
    const float bc = b_in[c];
#pragma unroll
    for (int rr = 0; rr < 8; ++rr) acc[rr] = bc;

#pragma unroll
    for (int k4 = 0; k4 < CIN; k4 += 4) {
        const float w0 = Wl[(k4 + 0) * HID + c];
        const float w1 = Wl[(k4 + 1) * HID + c];
        const float w2 = Wl[(k4 + 2) * HID + c];
        const float w3 = Wl[(k4 + 3) * HID + c];
#pragma unroll
        for (int rr = 0; rr < 8; ++rr) {
            const float4 xv = *(const float4*)&xl[rg * 8 + rr][k4];
            acc[rr] = fmaf(xv.w, w3, fmaf(xv.z, w2, fmaf(xv.y, w1, fmaf(xv.x, w0, acc[rr]))));
        }
    }

    // f16 store: thread owns 8 consecutive j of row (b,c) -> one 16B store
    half8 hv;
#pragma unroll
    for (int rr = 0; rr < 8; ++rr) hv[rr] = (_Float16)acc[rr];
    *(half8*)(hH + (size_t)(b * HID + c) * NN + j0 + rg * 8) = hv;

    // alphas (f32), reduce over d=32 lanes
    const float as = att_src[c], ad = att_dst[c];
#pragma unroll
    for (int rr = 0; rr < 8; ++rr) {
        float vs = acc[rr] * as, vd = acc[rr] * ad;
#pragma unroll
        for (int m = 16; m >= 1; m >>= 1) {
            vs += __shfl_xor(vs, m, 64);
            vd += __shfl_xor(vd, m, 64);
        }
        if ((t & 31) == 0) {
            srcA[(size_t)(b * HEADS + h) * NN + j0 + rg * 8 + rr] = vs;
            dstA[(size_t)(b * HEADS + h) * NN + j0 + rg * 8 + rr] = vd;
        }
    }
}

// ---------------- k_adjb: adj int32 -> bitmask (bit j of word j/32) ----------------
__global__ __launch_bounds__(256) void k_adjb(const int* __restrict__ adj,
                                              unsigned* __restrict__ adjb)
{
    const int wid = blockIdx.x * 4 + (threadIdx.x >> 6);
    const int lane = threadIdx.x & 63;
    const int i = wid >> 5;            // row
    const int jc = wid & 31;           // 64-col chunk
    const int a = adj[(size_t)i * NN + jc * 64 + lane];
    const unsigned long long m = __ballot(a != 0);
    if (lane == 0) {
        *(uint2*)(adjb + (size_t)i * (NN / 32) + jc * 2) =
            make_uint2((unsigned)m, (unsigned)(m >> 32));
    }
}

// ---------------- Kernel B: MFMA flash-GAT ----------------
// block = 512 thr = 8 waves: wave w -> head h=w&3, j-half jh=w>>2. Block = (b, 16 i-rows).
__global__ __launch_bounds__(512, 4) void k_attn(
    const unsigned* __restrict__ adjb, const _Float16* __restrict__ hH,
    const float* __restrict__ srcA, const float* __restrict__ dstA,
    float* __restrict__ attO)
{
    __shared__ float ldst[HEADS][NN];       // 32 KB (dst * log2e)
    __shared__ float redA[8][16][36];       // 18.4 KB partial tiles
    __shared__ float redS[8][16];           // partial rowsums

    const int t = threadIdx.x;
    const int lane = t & 63;
    const int w = t >> 6;
    const int h = w & 3;
    const int jh = w >> 2;
    const int b = blockIdx.x >> 7;
    const int i0 = (blockIdx.x & 127) * 16;

    {   // stage this wave's own (head, j-half) quarter of dst (read back only by itself)
        const float4* s4 = (const float4*)(dstA + (size_t)(b * HEADS + h) * NN + jh * 1024);
        float4* d4 = (float4*)&ldst[h][jh * 1024];
#pragma unroll
        for (int u = 0; u < 4; ++u) {
            float4 v = s4[lane + 64 * u];
            v.x *= LOG2E; v.y *= LOG2E; v.z *= LOG2E; v.w *= LOG2E;
            d4[lane + 64 * u] = v;
        }
    }

    const int r16 = lane & 15;
    const int g = lane >> 4;
    const float srci = srcA[(size_t)(b * HEADS + h) * NN + i0 + r16] * LOG2E;
    const uint2* adjrow2 = (const uint2*)(adjb + (size_t)(i0 + r16) * (NN / 32)) + jh * 16;
    const _Float16* bbase = hH + ((size_t)(b * HID) + h * DD + r16) * NN + jh * 1024 + 8 * g;

    f32x4 acc0 = {0.f, 0.f, 0.f, 0.f};
    f32x4 acc1 = {0.f, 0.f, 0.f, 0.f};
    f32x4 accS = {0.f, 0.f, 0.f, 0.f};
    const half8 ones = {(_Float16)1.f, (_Float16)1.f, (_Float16)1.f, (_Float16)1.f,
                        (_Float16)1.f, (_Float16)1.f, (_Float16)1.f, (_Float16)1.f};

    for (int jt2 = 0; jt2 < 1024; jt2 += 64) {
        const uint2 aw2 = adjrow2[jt2 >> 6];
#pragma unroll
        for (int s2 = 0; s2 < 2; ++s2) {
            const int jt = jt2 + 32 * s2;
            const unsigned bits = (s2 ? aw2.y : aw2.x) >> (8 * g);
            const float* dp = &ldst[h][jh * 1024 + jt + 8 * g];
            const float4 dl0 = *(const float4*)dp;
            const float4 dl1 = *(const float4*)(dp + 4);
            const half8 b0 = *(const half8*)(bbase + jt);
            const half8 b1 = *(const half8*)(bbase + 16 * NN + jt);
            const float dv[8] = {dl0.x, dl0.y, dl0.z, dl0.w, dl1.x, dl1.y, dl1.z, dl1.w};
            float wv[8];
#pragma unroll
            for (int e = 0; e < 8; ++e) {
                float s = srci + dv[e];
                s = fmaxf(s, 0.2f * s);                    // leaky relu
                s = (bits & (1u << e)) ? s : NEGBIG;       // mask -> exp2 ~ 0
                wv[e] = __builtin_amdgcn_exp2f(s);
            }
            const half2 p0 = __builtin_bit_cast(half2, __builtin_amdgcn_cvt_pkrtz(wv[0], wv[1]));
            const half2 p1 = __builtin_bit_cast(half2, __builtin_amdgcn_cvt_pkrtz(wv[2], wv[3]));
            const half2 p2 = __builtin_bit_cast(half2, __builtin_amdgcn_cvt_pkrtz(wv[4], wv[5]));
            const half2 p3 = __builtin_bit_cast(half2, __builtin_amdgcn_cvt_pkrtz(wv[6], wv[7]));
            half8 af;
            af[0] = p0[0]; af[1] = p0[1]; af[2] = p1[0]; af[3] = p1[1];
            af[4] = p2[0]; af[5] = p2[1]; af[6] = p3[0]; af[7] = p3[1];
            acc0 = __builtin_amdgcn_mfma_f32_16x16x32_f16(af, b0, acc0, 0, 0, 0);
            acc1 = __builtin_amdgcn_mfma_f32_16x16x32_f16(af, b1, acc1, 0, 0, 0);
            accS = __builtin_amdgcn_mfma_f32_16x16x32_f16(af, ones, accS, 0, 0, 0);
        }
    }

    // write partial tiles (C layout: col=lane&15, row=4*(lane>>4)+reg)
#pragma unroll
    for (int r = 0; r < 4; ++r) {
        redA[w][4 * g + r][r16]      = acc0[r];
        redA[w][4 * g + r][16 + r16] = acc1[r];
    }
    if (r16 == 0) {
#pragma unroll
        for (int r = 0; r < 4; ++r) redS[w][4 * g + r] = accS[r];
    }
    __syncthreads();

    // combine j-halves, normalize, store (512 thr x 4 elems = 16 rows x 128)
    {
        const int i = t >> 5;
        const int q = t & 31;
        const int h2 = q >> 3;
        const int d0 = (q & 7) * 4;
        const float4 v0 = *(const float4*)&redA[h2][i][d0];
        const float4 v1 = *(const float4*)&redA[h2 + 4][i][d0];
        const float rs = redS[h2][i] + redS[h2 + 4][i];
        const float inv = __builtin_amdgcn_rcpf(rs);
        float4 o;
        o.x = (v0.x + v1.x) * inv; o.y = (v0.y + v1.y) * inv;
        o.z = (v0.z + v1.z) * inv; o.w = (v0.w + v1.w) * inv;
        *(float4*)(attO + (size_t)(b * NN + i0 + i) * HID + h2 * DD + d0) = o;
    }
}

// ---------------- init d_out with bias ----------------
__global__ void k_init(const float* __restrict__ b_out, float* __restrict__ dout)
{
    const int t = threadIdx.x; // 64 threads
    dout[t] = b_out[t & 15];
}

// ---------------- Kernel C: final projection ----------------
__global__ __launch_bounds__(256) void k_proj(
    const float* __restrict__ attO, const float* __restrict__ W_out,
    float* __restrict__ dout)
{
    const int t = threadIdx.x;
    const int k0 = blockIdx.x * (KTOT / CCH);   // 1024 k per block

    float acc[64];
#pragma unroll
    for (int r = 0; r < 64; ++r) acc[r] = 0.f;

    for (int s = 0; s < (KTOT / CCH) / 256; ++s) {
        const int k = k0 + s * 256 + t;
        float a[4];
#pragma unroll
        for (int b = 0; b < 4; ++b) a[b] = attO[(size_t)b * KTOT + k];
        const float4* wr = (const float4*)(W_out + (size_t)k * NQ);
        float wf[16];
#pragma unroll
        for (int q4 = 0; q4 < 4; ++q4) {
            const float4 w4 = wr[q4];
            wf[q4 * 4 + 0] = w4.x; wf[q4 * 4 + 1] = w4.y;
            wf[q4 * 4 + 2] = w4.z; wf[q4 * 4 + 3] = w4.w;
        }
#pragma unroll
        for (int b = 0; b < 4; ++b)
#pragma unroll
            for (int q = 0; q < 16; ++q)
                acc[b * 16 + q] = fmaf(a[b], wf[q], acc[b * 16 + q]);
    }

    const int lane = t & 63, wave = t >> 6;
    __shared__ float red[4][64];
#pragma unroll
    for (int r = 0; r < 64; ++r) {
        float v = acc[r];
        v += __shfl_down(v, 32, 64);
        v += __shfl_down(v, 16, 64);
        v += __shfl_down(v, 8, 64);
        v += __shfl_down(v, 4, 64);
        v += __shfl_down(v, 2, 64);
        v += __shfl_down(v, 1, 64);
        if (lane == 0) red[wave][r] = v;
    }
    __syncthreads();
    if (t < 64) {
        const float v = red[0][t] + red[1][t] + red[2][t] + red[3][t];
        atomicAdd(&dout[t], v);
    }
}

extern "C" void kernel_launch(void* const* d_in, const int* in_sizes, int n_in,
                              void* d_out, int out_size, void* d_ws, size_t ws_size,
                              hipStream_t stream)
{
    const float* x       = (const float*)d_in[0];
    const int*   adj     = (const int*)d_in[1];
    const float* W_in    = (const float*)d_in[2];
    const float* b_in    = (const float*)d_in[3];
    const float* att_src = (const float*)d_in[4];
    const float* att_dst = (const float*)d_in[5];
    const float* W_out   = (const float*)d_in[6];
    const float* b_out   = (const float*)d_in[7];
    float* out = (float*)d_out;

    float* ws = (float*)d_ws;
    float* attO = ws;                                  // 1,048,576 f32 (4 MB)
    float* srcA = ws + (size_t)BB * HID * NN;          // 32768 f32
    float* dstA = srcA + (size_t)BB * HEADS * NN;      // 32768 f32
    _Float16* hH = (_Float16*)(dstA + (size_t)BB * HEADS * NN);   // 1,048,576 f16 (2 MB)
    unsigned* adjbw = (unsigned*)((char*)hH + sizeof(_Float16) * (size_t)BB * HID * NN); // 512 KB

    k_hidden<<<BB * NN / 16, 256, 0, stream>>>(x, W_in, b_in, att_src, att_dst, hH, srcA, dstA);
    k_adjb<<<NN * (NN / 64) / 4, 256, 0, stream>>>(adj, adjbw);
    k_attn<<<BB * (NN / 16), 512, 0, stream>>>(adjbw, hH, srcA, dstA, attO);
    k_init<<<1, 64, 0, stream>>>(b_out, out);
    k_proj<<<CCH, 256, 0, stream>>>(attO, W_out, out);
}